// Round 6
// baseline (183.403 us; speedup 1.0000x reference)
//
#include <hip/hip_runtime.h>

// Problem constants
#define BB 4
#define SS 2048
#define DM 256
#define NH 4
#define DH 64
#define NROW (BB*SS)              // 8192
#define NE   (3*DM)               // 768
#define BH   (BB*NH)              // 16
#define HEAD_ELEMS (BH*SS*DH)     // 2097152 per tensor
#define NQROWS (BH*SS)            // 32768

typedef _Float16 half_t;
typedef __attribute__((ext_vector_type(8))) _Float16 half8;
typedef __attribute__((ext_vector_type(4))) _Float16 half4;
typedef __attribute__((ext_vector_type(4))) float floatx4;

#define VPAD 136                  // qkv v-transpose LDS stride (128+8 halfs)

// ---------------------------------------------------------------------------
// prep: one-shot conversion  x -> (x_hi, x_lo) fp16,  W -> fp16.
// ---------------------------------------------------------------------------
__global__ __launch_bounds__(256) void prep(const float* __restrict__ x,
                                            const float* __restrict__ W,
                                            half_t* __restrict__ xh,
                                            half_t* __restrict__ xl,
                                            half_t* __restrict__ wh) {
    int gtid = blockIdx.x * 256 + threadIdx.x;    // 0..524287
    {
        int i = gtid * 4;
        float4 v = *(const float4*)&x[i];
        half4 h, l;
        h.x = (half_t)v.x; l.x = (half_t)(v.x - (float)h.x);
        h.y = (half_t)v.y; l.y = (half_t)(v.y - (float)h.y);
        h.z = (half_t)v.z; l.z = (half_t)(v.z - (float)h.z);
        h.w = (half_t)v.w; l.w = (half_t)(v.w - (float)h.w);
        *(half4*)&xh[i] = h;
        *(half4*)&xl[i] = l;
    }
    if (gtid < NE * DM / 4) {
        int i = gtid * 4;
        float4 v = *(const float4*)&W[i];
        half4 h;
        h.x = (half_t)v.x; h.y = (half_t)v.y;
        h.z = (half_t)v.z; h.w = (half_t)v.w;
        *(half4*)&wh[i] = h;
    }
}

// ---------------------------------------------------------------------------
// QKV projection, fp16 MFMA, direct global->VGPR fragments, NO LDS / NO
// barriers in the K-loop. Wave = 32 rows (2 strips) x 64 features.
// A-frags (x hi/lo): 16B/lane, 16 rows x 64B contiguous chunks (coalesced).
// B-frags (W): identical pattern; W strip is L1/L2-hot (shared by all blocks).
// Epilogue: q(*0.125)/k direct scatter; v transposes via LDS (only barrier).
// ---------------------------------------------------------------------------
__global__ __launch_bounds__(256) void qkv_proj(const half_t* __restrict__ xh,
                                                const half_t* __restrict__ xl,
                                                const half_t* __restrict__ whg,
                                                const float* __restrict__ bias,
                                                half_t* __restrict__ qh,
                                                half_t* __restrict__ kh,
                                                half_t* __restrict__ vt) {
    __shared__ __align__(16) half_t Vtile[64 * VPAD];  // epilogue-only (v part)

    const int nb   = blockIdx.y * 64;
    const int tid  = threadIdx.x;
    const int wid  = tid >> 6;
    const int lane = tid & 63;
    const int quad = lane >> 4;
    const int col  = lane & 15;
    const int rb   = blockIdx.x * 128 + wid * 32;   // this wave's 32 rows

    floatx4 acc[2][4];
    #pragma unroll
    for (int st = 0; st < 2; ++st)
        #pragma unroll
        for (int t = 0; t < 4; ++t) acc[st][t] = (floatx4){0.f, 0.f, 0.f, 0.f};

    #pragma unroll
    for (int k0 = 0; k0 < DM; k0 += 32) {
        half8 ah[2], al[2], bw[4];
        #pragma unroll
        for (int st = 0; st < 2; ++st) {
            const size_t ro = (size_t)(rb + st * 16 + col) * DM + k0 + quad * 8;
            ah[st] = *(const half8*)&xh[ro];
            al[st] = *(const half8*)&xl[ro];
        }
        #pragma unroll
        for (int t = 0; t < 4; ++t)
            bw[t] = *(const half8*)&whg[(size_t)(nb + t * 16 + col) * DM + k0 + quad * 8];
        #pragma unroll
        for (int t = 0; t < 4; ++t)
            #pragma unroll
            for (int st = 0; st < 2; ++st) {
                acc[st][t] = __builtin_amdgcn_mfma_f32_16x16x32_f16(ah[st], bw[t], acc[st][t], 0, 0, 0);
                acc[st][t] = __builtin_amdgcn_mfma_f32_16x16x32_f16(al[st], bw[t], acc[st][t], 0, 0, 0);
            }
    }

    const int part = nb >> 8;           // block-uniform: 0=q 1=k 2=v
    if (part != 2) {
        #pragma unroll
        for (int st = 0; st < 2; ++st)
            #pragma unroll
            for (int t = 0; t < 4; ++t) {
                int e    = nb + t * 16 + col;
                float be = bias[e];
                int dm   = e & 255;
                int h    = dm >> 6;
                int dh   = dm & 63;
                #pragma unroll
                for (int r = 0; r < 4; ++r) {
                    int row = rb + st * 16 + quad * 4 + r;
                    int b   = row >> 11;
                    int s   = row & 2047;
                    int bh_ = b * NH + h;
                    float val = acc[st][t][r] + be;
                    if (part == 0) {
                        qh[((size_t)bh_ * SS + s) * DH + dh] = (half_t)(val * 0.125f);
                    } else {
                        kh[((size_t)bh_ * SS + s) * DH + dh] = (half_t)val;
                    }
                }
            }
    } else {
        // v: transpose 64(d) x 128(s) tile through LDS -> coalesced vt stores
        #pragma unroll
        for (int st = 0; st < 2; ++st)
            #pragma unroll
            for (int t = 0; t < 4; ++t) {
                int e    = nb + t * 16 + col;
                float be = bias[e];
                #pragma unroll
                for (int r = 0; r < 4; ++r)
                    Vtile[(t * 16 + col) * VPAD + wid * 32 + st * 16 + quad * 4 + r] =
                        (half_t)(acc[st][t][r] + be);
            }
        __syncthreads();
        const int s0  = (blockIdx.x * 128) & 2047;
        const int b   = (blockIdx.x * 128) >> 11;
        const int h   = (nb >> 6) & 3;
        const int bh_ = b * NH + h;
        #pragma unroll
        for (int i = 0; i < 4; ++i) {
            int gi = tid + 256 * i;        // 0..1023
            int rr = gi >> 4;              // d 0..63
            int cc = (gi & 15) * 8;        // s chunk 0..120
            *(half8*)&vt[((size_t)bh_ * DH + rr) * SS + s0 + cc] =
                *(const half8*)&Vtile[rr * VPAD + cc];
        }
    }
}

// ---------------------------------------------------------------------------
// Flash attention, fp16 MFMA, S^T trick, split-K(2), 32 q/wave.
// NO LDS, NO barriers: K/V fragments loaded directly global->VGPR.
//   K A-frags: 16B/lane, 16 rows x 64B chunks (perfectly coalesced).
//   V^T B-frags: 8B/lane; t-loop consumes full 64B lines (L1-served).
// K frags double-buffered one iteration ahead; V frags load at iteration top
// and are consumed ~400 cyc later (post SQK+softmax). Wave-uniform alpha-skip
// bypasses the O-rescale when the running max is unchanged (exact).
// ---------------------------------------------------------------------------
__global__ __launch_bounds__(128, 2) void attn(const half_t* __restrict__ qh,
                                               const half_t* __restrict__ kh,
                                               const half_t* __restrict__ vt,
                                               half_t* __restrict__ pO,
                                               float* __restrict__ mst,
                                               float* __restrict__ lst) {
    const int q0   = blockIdx.x * 64;
    const int bh   = blockIdx.y;
    const int kz   = blockIdx.z;
    const size_t base = (size_t)bh * SS * DH;
    const int tid  = threadIdx.x;
    const int wid  = tid >> 6;    // 0..1
    const int lane = tid & 63;
    const int quad = lane >> 4;
    const int col  = lane & 15;
    const int ktBeg = kz * (SS / 2);
    const int ktEnd = ktBeg + (SS / 2);

    // Q B-frags: 2 strips of 16 q rows (pre-scaled by 0.125)
    half8 bq[2][2];
    #pragma unroll
    for (int st = 0; st < 2; ++st) {
        int s = q0 + wid * 32 + st * 16 + col;
        bq[st][0] = *(const half8*)&qh[base + (size_t)s * DH + quad * 8];
        bq[st][1] = *(const half8*)&qh[base + (size_t)s * DH + 32 + quad * 8];
    }

    // Preload K frags for tile ktBeg: ck[h][t], h = d-half (0..1)
    half8 ck[2][4];
    #pragma unroll
    for (int t = 0; t < 4; ++t) {
        const size_t kro = base + (size_t)(ktBeg + t * 16 + col) * DH + quad * 8;
        ck[0][t] = *(const half8*)&kh[kro];
        ck[1][t] = *(const half8*)&kh[kro + 32];
    }

    float m_i[2] = {-3.0e38f, -3.0e38f};
    float l_i[2] = {0.f, 0.f};
    floatx4 o[2][4];
    #pragma unroll
    for (int st = 0; st < 2; ++st)
        #pragma unroll
        for (int dt = 0; dt < 4; ++dt) o[st][dt] = (floatx4){0.f, 0.f, 0.f, 0.f};

    for (int kt = ktBeg; kt < ktEnd; kt += 64) {
        // V frags for THIS tile (consumed after SQK+softmax -> latency hidden)
        half4 cv[4][4];   // [t][dt]
        #pragma unroll
        for (int t = 0; t < 4; ++t)
            #pragma unroll
            for (int dt = 0; dt < 4; ++dt)
                cv[t][dt] = *(const half4*)&vt[base + (size_t)(dt * 16 + col) * SS +
                                               kt + t * 16 + quad * 4];

        // S^T = K · Q^T (ck loaded one iteration ago)
        floatx4 sc[2][4];
        #pragma unroll
        for (int t = 0; t < 4; ++t)
            #pragma unroll
            for (int st = 0; st < 2; ++st) {
                floatx4 c = (floatx4){0.f, 0.f, 0.f, 0.f};
                c = __builtin_amdgcn_mfma_f32_16x16x32_f16(ck[0][t], bq[st][0], c, 0, 0, 0);
                c = __builtin_amdgcn_mfma_f32_16x16x32_f16(ck[1][t], bq[st][1], c, 0, 0, 0);
                sc[st][t] = c;
            }

        // Prefetch next K tile (branchless: last iter re-fetches ktBeg, unused)
        const int ktn = (kt + 64 < ktEnd) ? kt + 64 : ktBeg;
        half8 nk[2][4];
        #pragma unroll
        for (int t = 0; t < 4; ++t) {
            const size_t kro = base + (size_t)(ktn + t * 16 + col) * DH + quad * 8;
            nk[0][t] = *(const half8*)&kh[kro];
            nk[1][t] = *(const half8*)&kh[kro + 32];
        }

        // Online softmax per strip, with wave-uniform alpha-skip
        half4 pa[2][4];
        #pragma unroll
        for (int st = 0; st < 2; ++st) {
            float mloc = -3.0e38f;
            #pragma unroll
            for (int t = 0; t < 4; ++t)
                #pragma unroll
                for (int r = 0; r < 4; ++r)
                    mloc = fmaxf(mloc, sc[st][t][r]);
            mloc = fmaxf(mloc, __shfl_xor(mloc, 16));
            mloc = fmaxf(mloc, __shfl_xor(mloc, 32));

            if (__any(mloc > m_i[st])) {
                float m_new = fmaxf(m_i[st], mloc);
                float alpha = __expf(m_i[st] - m_new);
                m_i[st] = m_new;
                l_i[st] *= alpha;
                float ar[4];
                #pragma unroll
                for (int i = 0; i < 4; ++i) ar[i] = __shfl(alpha, quad * 4 + i);
                #pragma unroll
                for (int dt = 0; dt < 4; ++dt)
                    #pragma unroll
                    for (int i = 0; i < 4; ++i)
                        o[st][dt][i] *= ar[i];
            }

            float m_new = m_i[st];
            float rsum = 0.f;
            #pragma unroll
            for (int t = 0; t < 4; ++t) {
                float p0 = __expf(sc[st][t][0] - m_new);
                float p1 = __expf(sc[st][t][1] - m_new);
                float p2 = __expf(sc[st][t][2] - m_new);
                float p3 = __expf(sc[st][t][3] - m_new);
                rsum += p0 + p1 + p2 + p3;
                pa[st][t] = (half4){(half_t)p0, (half_t)p1, (half_t)p2, (half_t)p3};
            }
            rsum += __shfl_xor(rsum, 16);
            rsum += __shfl_xor(rsum, 32);
            l_i[st] += rsum;
        }

        // O += P · V
        #pragma unroll
        for (int t = 0; t < 4; ++t)
            #pragma unroll
            for (int dt = 0; dt < 4; ++dt) {
                half4 bv = cv[t][dt];
                #pragma unroll
                for (int st = 0; st < 2; ++st)
                    o[st][dt] = __builtin_amdgcn_mfma_f32_16x16x16f16(pa[st][t], bv, o[st][dt], 0, 0, 0);
            }

        // Rotate K double-buffer
        #pragma unroll
        for (int t = 0; t < 4; ++t) { ck[0][t] = nk[0][t]; ck[1][t] = nk[1][t]; }
    }

    // Epilogue: normalized partial O (fp16) + stats
    const size_t pbase = (size_t)kz * HEAD_ELEMS + base;
    #pragma unroll
    for (int st = 0; st < 2; ++st) {
        float inv = 1.0f / l_i[st];
        float ir[4];
        #pragma unroll
        for (int i = 0; i < 4; ++i) ir[i] = __shfl(inv, quad * 4 + i);
        #pragma unroll
        for (int dt = 0; dt < 4; ++dt)
            #pragma unroll
            for (int i = 0; i < 4; ++i) {
                int row = q0 + wid * 32 + st * 16 + quad * 4 + i;
                pO[pbase + (size_t)row * DH + dt * 16 + col] = (half_t)(o[st][dt][i] * ir[i]);
            }
        if (quad == 0) {
            int row = q0 + wid * 32 + st * 16 + col;
            int idx = kz * NQROWS + bh * SS + row;
            mst[idx] = m_i[st];
            lst[idx] = l_i[st];
        }
    }
}

// ---------------------------------------------------------------------------
// merge: combine the two kz partials. 262144 threads, 8 d-elems each.
// ---------------------------------------------------------------------------
__global__ __launch_bounds__(256) void merge(const half_t* __restrict__ pO,
                                             const float* __restrict__ mst,
                                             const float* __restrict__ lst,
                                             float* __restrict__ out) {
    int gid = blockIdx.x * 256 + threadIdx.x;   // 0..262143
    int row = gid >> 3;                         // bh*SS + s
    int dc  = (gid & 7) * 8;
    float m1 = mst[row], m2 = mst[NQROWS + row];
    float l1 = lst[row], l2 = lst[NQROWS + row];
    float M  = fmaxf(m1, m2);
    float w1 = l1 * __expf(m1 - M);
    float w2 = l2 * __expf(m2 - M);
    float inv = 1.0f / (w1 + w2);
    float a = w1 * inv, b = w2 * inv;
    half8 o1 = *(const half8*)&pO[(size_t)row * DH + dc];
    half8 o2 = *(const half8*)&pO[(size_t)HEAD_ELEMS + (size_t)row * DH + dc];
    float4 r0, r1;
    r0.x = a * (float)o1[0] + b * (float)o2[0];
    r0.y = a * (float)o1[1] + b * (float)o2[1];
    r0.z = a * (float)o1[2] + b * (float)o2[2];
    r0.w = a * (float)o1[3] + b * (float)o2[3];
    r1.x = a * (float)o1[4] + b * (float)o2[4];
    r1.y = a * (float)o1[5] + b * (float)o2[5];
    r1.z = a * (float)o1[6] + b * (float)o2[6];
    r1.w = a * (float)o1[7] + b * (float)o2[7];
    *(float4*)&out[(size_t)row * DH + dc]     = r0;
    *(float4*)&out[(size_t)row * DH + dc + 4] = r1;
}

extern "C" void kernel_launch(void* const* d_in, const int* in_sizes, int n_in,
                              void* d_out, int out_size, void* d_ws, size_t ws_size,
                              hipStream_t stream) {
    const float* x  = (const float*)d_in[0];   // [4,2048,256]
    const float* Wq = (const float*)d_in[1];   // [768,256]
    const float* bq = (const float*)d_in[2];   // [768]
    float* out = (float*)d_out;                // [4,4,2048,64]

    // ws layout (half_t units):
    //   qh 0..2M | kh 2M..4M | vt 4M..6M | xh 6M..8M | xl 8M..10M | Wh 10M..10.19M
    //   pO[2] aliases xh/xl (dead after qkv_proj); stats f32 after Wh.
    half_t* qh  = (half_t*)d_ws;
    half_t* kh  = qh + (size_t)HEAD_ELEMS;
    half_t* vt  = kh + (size_t)HEAD_ELEMS;
    half_t* xh  = vt + (size_t)HEAD_ELEMS;
    half_t* xl  = xh + (size_t)HEAD_ELEMS;
    half_t* whp = xl + (size_t)HEAD_ELEMS;             // 196608 halfs
    half_t* pO  = xh;                                  // alias: 2 x HEAD_ELEMS
    float*  mst = (float*)((char*)d_ws + 21364736);    // 2*32768 floats
    float*  lst = mst + 2 * NQROWS;

    prep<<<2048, 256, 0, stream>>>(x, Wq, xh, xl, whp);
    qkv_proj<<<dim3(NROW / 128, NE / 64), 256, 0, stream>>>(xh, xl, whp, bq, qh, kh, vt);
    attn<<<dim3(SS / 64, BH, 2), 128, 0, stream>>>(qh, kh, vt, pO, mst, lst);
    merge<<<1024, 256, 0, stream>>>(pO, mst, lst, out);
}

// Round 8
// 126.118 us; speedup vs baseline: 1.4542x; 1.4542x over previous
//
#include <hip/hip_runtime.h>

// Problem constants
#define BB 4
#define SS 2048
#define DM 256
#define NH 4
#define DH 64
#define NROW (BB*SS)              // 8192
#define NE   (3*DM)               // 768
#define BH   (BB*NH)              // 16
#define HEAD_ELEMS (BH*SS*DH)     // 2097152 per tensor
#define NQROWS (BH*SS)            // 32768

typedef _Float16 half_t;
typedef __attribute__((ext_vector_type(8))) _Float16 half8;
typedef __attribute__((ext_vector_type(4))) _Float16 half4;
typedef __attribute__((ext_vector_type(4))) float floatx4;

#define KPAD 72                   // LDS stride in halfs (144 B, 16B-aligned rows)
// q pre-scale: 1/sqrt(64) * log2(e)  -> softmax runs in exp2 domain
#define QSCALE 0.1803368801111120f

// ---------------------------------------------------------------------------
// prep: one-shot conversion  x -> (x_hi, x_lo) fp16,  W -> fp16.
// ---------------------------------------------------------------------------
__global__ __launch_bounds__(256) void prep(const float* __restrict__ x,
                                            const float* __restrict__ W,
                                            half_t* __restrict__ xh,
                                            half_t* __restrict__ xl,
                                            half_t* __restrict__ wh) {
    int gtid = blockIdx.x * 256 + threadIdx.x;    // 0..524287
    {
        int i = gtid * 4;
        float4 v = *(const float4*)&x[i];
        half4 h, l;
        h.x = (half_t)v.x; l.x = (half_t)(v.x - (float)h.x);
        h.y = (half_t)v.y; l.y = (half_t)(v.y - (float)h.y);
        h.z = (half_t)v.z; l.z = (half_t)(v.z - (float)h.z);
        h.w = (half_t)v.w; l.w = (half_t)(v.w - (float)h.w);
        *(half4*)&xh[i] = h;
        *(half4*)&xl[i] = l;
    }
    if (gtid < NE * DM / 4) {
        int i = gtid * 4;
        float4 v = *(const float4*)&W[i];
        half4 h;
        h.x = (half_t)v.x; h.y = (half_t)v.y;
        h.z = (half_t)v.z; h.w = (half_t)v.w;
        *(half4*)&wh[i] = h;
    }
}

// ---------------------------------------------------------------------------
// QKV projection (round-5 LDS structure), fp16 MFMA, hi/lo-split x.
// q is pre-scaled by QSCALE (softmax in exp2 domain).
// ---------------------------------------------------------------------------
__global__ __launch_bounds__(256) void qkv_proj(const half_t* __restrict__ xh,
                                                const half_t* __restrict__ xl,
                                                const half_t* __restrict__ whg,
                                                const float* __restrict__ bias,
                                                half_t* __restrict__ qh,
                                                half_t* __restrict__ kh,
                                                half_t* __restrict__ vt) {
    __shared__ __align__(16) half_t Xh[64 * KPAD];
    __shared__ __align__(16) half_t Xl[64 * KPAD];
    __shared__ __align__(16) half_t Wh[64 * KPAD];

    const int rb   = blockIdx.x * 64;
    const int nb   = blockIdx.y * 64;
    const int tid  = threadIdx.x;
    const int wid  = tid >> 6;
    const int lane = tid & 63;
    const int quad = lane >> 4;
    const int col  = lane & 15;

    floatx4 acc[4];
    #pragma unroll
    for (int t = 0; t < 4; ++t) acc[t] = (floatx4){0.f, 0.f, 0.f, 0.f};

    for (int k0 = 0; k0 < DM; k0 += 64) {
        __syncthreads();
        #pragma unroll
        for (int i = 0; i < 2; ++i) {
            int gi = tid + 256 * i;        // 0..511
            int r  = gi >> 3;              // 0..63
            int c8 = (gi & 7) * 8;         // 0..56
            *(half8*)&Xh[r * KPAD + c8] = *(const half8*)&xh[(size_t)(rb + r) * DM + k0 + c8];
            *(half8*)&Xl[r * KPAD + c8] = *(const half8*)&xl[(size_t)(rb + r) * DM + k0 + c8];
            *(half8*)&Wh[r * KPAD + c8] = *(const half8*)&whg[(size_t)(nb + r) * DM + k0 + c8];
        }
        __syncthreads();

        half8 ah0 = *(const half8*)&Xh[(wid * 16 + col) * KPAD + quad * 8];
        half8 ah1 = *(const half8*)&Xh[(wid * 16 + col) * KPAD + 32 + quad * 8];
        half8 al0 = *(const half8*)&Xl[(wid * 16 + col) * KPAD + quad * 8];
        half8 al1 = *(const half8*)&Xl[(wid * 16 + col) * KPAD + 32 + quad * 8];

        #pragma unroll
        for (int t = 0; t < 4; ++t) {
            half8 bh0 = *(const half8*)&Wh[(t * 16 + col) * KPAD + quad * 8];
            half8 bh1 = *(const half8*)&Wh[(t * 16 + col) * KPAD + 32 + quad * 8];
            acc[t] = __builtin_amdgcn_mfma_f32_16x16x32_f16(ah0, bh0, acc[t], 0, 0, 0);
            acc[t] = __builtin_amdgcn_mfma_f32_16x16x32_f16(ah1, bh1, acc[t], 0, 0, 0);
            acc[t] = __builtin_amdgcn_mfma_f32_16x16x32_f16(al0, bh0, acc[t], 0, 0, 0);
            acc[t] = __builtin_amdgcn_mfma_f32_16x16x32_f16(al1, bh1, acc[t], 0, 0, 0);
        }
    }

    const int part = nb >> 8;           // block-uniform: 0=q 1=k 2=v
    const int mloc = wid * 16 + quad * 4;
    if (part != 2) {
        #pragma unroll
        for (int t = 0; t < 4; ++t) {
            int e    = nb + t * 16 + col;
            float be = bias[e];
            int dm   = e & 255;
            int h    = dm >> 6;
            int dh   = dm & 63;
            #pragma unroll
            for (int r = 0; r < 4; ++r) {
                int row = rb + mloc + r;
                int b   = row >> 11;
                int s   = row & 2047;
                int bh_ = b * NH + h;
                float val = acc[t][r] + be;
                if (part == 0) {
                    qh[((size_t)bh_ * SS + s) * DH + dh] = (half_t)(val * QSCALE);
                } else {
                    kh[((size_t)bh_ * SS + s) * DH + dh] = (half_t)val;
                }
            }
        }
    } else {
        __syncthreads();
        #pragma unroll
        for (int t = 0; t < 4; ++t) {
            int e    = nb + t * 16 + col;
            float be = bias[e];
            #pragma unroll
            for (int r = 0; r < 4; ++r)
                Xh[(t * 16 + col) * KPAD + mloc + r] = (half_t)(acc[t][r] + be);
        }
        __syncthreads();
        const int b   = rb >> 11;
        const int s0  = rb & 2047;
        const int h   = (nb >> 6) & 3;
        const int bh_ = b * NH + h;
        #pragma unroll
        for (int i = 0; i < 2; ++i) {
            int idx = tid + 256 * i;
            int rr  = idx >> 3;
            int cc8 = (idx & 7) * 8;
            *(half8*)&vt[((size_t)bh_ * DH + rr) * SS + s0 + cc8] =
                *(const half8*)&Xh[rr * KPAD + cc8];
        }
    }
}

// ---------------------------------------------------------------------------
// Flash attention, fp16 MFMA, S^T trick, split-K(2), 32 q/wave, 2-wave blocks.
// Double-buffered LDS tiles -> ONE barrier per iteration.
// Speculative exp2 softmax: exps issue against the old running max while the
// shuffle reduction is in flight; rare exact fixup (p*=beta, o*=ar).
// Row-sum l accumulated on the MFMA pipe via a ones-column B fragment.
// pO written unnormalized; merge folds in 1/l.
// ---------------------------------------------------------------------------
__global__ __launch_bounds__(128, 2) void attn(const half_t* __restrict__ qh,
                                               const half_t* __restrict__ kh,
                                               const half_t* __restrict__ vt,
                                               half_t* __restrict__ pO,
                                               float* __restrict__ mst,
                                               float* __restrict__ lst) {
    __shared__ __align__(16) half_t Ks[2][64 * KPAD];    // [kr][d]
    __shared__ __align__(16) half_t Vts[2][64 * KPAD];   // [d][kr]

    const int q0   = blockIdx.x * 64;
    const int bh   = blockIdx.y;
    const int kz   = blockIdx.z;
    const size_t base = (size_t)bh * SS * DH;
    const int tid  = threadIdx.x;
    const int wid  = tid >> 6;    // 0..1
    const int lane = tid & 63;
    const int quad = lane >> 4;
    const int col  = lane & 15;
    const int ktBeg = kz * (SS / 2);
    const int ktEnd = ktBeg + (SS / 2);
    const int NIT   = (SS / 2) / 64;   // 16

    int srr[4], scc[4];
    #pragma unroll
    for (int i = 0; i < 4; ++i) {
        int gi = tid + 128 * i;    // 0..511
        srr[i] = gi >> 3;          // 0..63
        scc[i] = (gi & 7) * 8;     // 0..56
    }

    // Q B-frags: 2 strips of 16 q rows (pre-scaled by QSCALE)
    half8 bq[2][2];
    #pragma unroll
    for (int st = 0; st < 2; ++st) {
        int s = q0 + wid * 32 + st * 16 + col;
        bq[st][0] = *(const half8*)&qh[base + (size_t)s * DH + quad * 8];
        bq[st][1] = *(const half8*)&qh[base + (size_t)s * DH + 32 + quad * 8];
    }

    // Load tile 0, stage into buf 0
    half8 ck[4], cv[4];
    #pragma unroll
    for (int i = 0; i < 4; ++i) {
        ck[i] = *(const half8*)&kh[base + (size_t)(ktBeg + srr[i]) * DH + scc[i]];
        cv[i] = *(const half8*)&vt[base + (size_t)srr[i] * SS + ktBeg + scc[i]];
    }
    #pragma unroll
    for (int i = 0; i < 4; ++i) {
        *(half8*)&Ks[0][srr[i] * KPAD + scc[i]]  = ck[i];
        *(half8*)&Vts[0][srr[i] * KPAD + scc[i]] = cv[i];
    }
    __syncthreads();
    // Prefetch tile 1 into regs
    {
        const int kt1 = (ktBeg + 64 < ktEnd) ? ktBeg + 64 : ktBeg;
        #pragma unroll
        for (int i = 0; i < 4; ++i) {
            ck[i] = *(const half8*)&kh[base + (size_t)(kt1 + srr[i]) * DH + scc[i]];
            cv[i] = *(const half8*)&vt[base + (size_t)srr[i] * SS + kt1 + scc[i]];
        }
    }

    const half4 bone = (half4){(half_t)1.f, (half_t)1.f, (half_t)1.f, (half_t)1.f};
    float m_i[2] = {0.f, 0.f};           // set from tile 0 (it==0 path)
    floatx4 lacc[2];
    floatx4 o[2][4];
    #pragma unroll
    for (int st = 0; st < 2; ++st) {
        lacc[st] = (floatx4){0.f, 0.f, 0.f, 0.f};
        #pragma unroll
        for (int dt = 0; dt < 4; ++dt) o[st][dt] = (floatx4){0.f, 0.f, 0.f, 0.f};
    }

    for (int it = 0; it < NIT; ++it) {
        const int buf = it & 1;
        const int kt  = ktBeg + it * 64;

        // Stage prefetched tile (it+1) into the other buffer (garbage on last
        // iter is never read).
        #pragma unroll
        for (int i = 0; i < 4; ++i) {
            *(half8*)&Ks[buf ^ 1][srr[i] * KPAD + scc[i]]  = ck[i];
            *(half8*)&Vts[buf ^ 1][srr[i] * KPAD + scc[i]] = cv[i];
        }

        // Issue global loads for tile it+2 (in flight across this compute)
        {
            int kt2 = kt + 128;
            if (kt2 >= ktEnd) kt2 = ktBeg;   // harmless refetch
            #pragma unroll
            for (int i = 0; i < 4; ++i) {
                ck[i] = *(const half8*)&kh[base + (size_t)(kt2 + srr[i]) * DH + scc[i]];
                cv[i] = *(const half8*)&vt[base + (size_t)srr[i] * SS + kt2 + scc[i]];
            }
        }

        // S^T = K · Q^T from Ks[buf]
        floatx4 sc[2][4];
        #pragma unroll
        for (int t = 0; t < 4; ++t) {
            half8 ak0 = *(const half8*)&Ks[buf][(t * 16 + col) * KPAD + quad * 8];
            half8 ak1 = *(const half8*)&Ks[buf][(t * 16 + col) * KPAD + 32 + quad * 8];
            #pragma unroll
            for (int st = 0; st < 2; ++st) {
                floatx4 c = (floatx4){0.f, 0.f, 0.f, 0.f};
                c = __builtin_amdgcn_mfma_f32_16x16x32_f16(ak0, bq[st][0], c, 0, 0, 0);
                c = __builtin_amdgcn_mfma_f32_16x16x32_f16(ak1, bq[st][1], c, 0, 0, 0);
                sc[st][t] = c;
            }
        }

        // Softmax (exp2 domain), speculative against old max
        half4 pa[2][4];
        #pragma unroll
        for (int st = 0; st < 2; ++st) {
            float mloc = fmaxf(fmaxf(fmaxf(sc[st][0][0], sc[st][0][1]), fmaxf(sc[st][0][2], sc[st][0][3])),
                               fmaxf(fmaxf(sc[st][1][0], sc[st][1][1]), fmaxf(sc[st][1][2], sc[st][1][3])));
            mloc = fmaxf(mloc,
                   fmaxf(fmaxf(fmaxf(sc[st][2][0], sc[st][2][1]), fmaxf(sc[st][2][2], sc[st][2][3])),
                         fmaxf(fmaxf(sc[st][3][0], sc[st][3][1]), fmaxf(sc[st][3][2], sc[st][3][3]))));
            float mx = fmaxf(mloc, __shfl_xor(mloc, 16));
            mx = fmaxf(mx, __shfl_xor(mx, 32));

            float p[16];
            if (it == 0) {
                m_i[st] = mx;
                #pragma unroll
                for (int t = 0; t < 4; ++t)
                    #pragma unroll
                    for (int r = 0; r < 4; ++r)
                        p[t * 4 + r] = exp2f(sc[st][t][r] - mx);
            } else {
                // speculative: exps vs old max, issued before mx resolves
                #pragma unroll
                for (int t = 0; t < 4; ++t)
                    #pragma unroll
                    for (int r = 0; r < 4; ++r)
                        p[t * 4 + r] = exp2f(sc[st][t][r] - m_i[st]);
                if (__any(mx > m_i[st])) {
                    float m_new = fmaxf(m_i[st], mx);
                    float beta  = exp2f(m_i[st] - m_new);
                    m_i[st] = m_new;
                    #pragma unroll
                    for (int j = 0; j < 16; ++j) p[j] *= beta;
                    float ar[4];
                    #pragma unroll
                    for (int i = 0; i < 4; ++i) ar[i] = __shfl(beta, quad * 4 + i);
                    #pragma unroll
                    for (int dt = 0; dt < 4; ++dt)
                        #pragma unroll
                        for (int i = 0; i < 4; ++i)
                            o[st][dt][i] *= ar[i];
                    #pragma unroll
                    for (int i = 0; i < 4; ++i) lacc[st][i] *= ar[i];
                }
            }
            #pragma unroll
            for (int t = 0; t < 4; ++t)
                pa[st][t] = (half4){(half_t)p[t * 4 + 0], (half_t)p[t * 4 + 1],
                                    (half_t)p[t * 4 + 2], (half_t)p[t * 4 + 3]};
        }

        // O += P · V from Vts[buf];  l += P · 1 on the MFMA pipe
        #pragma unroll
        for (int t = 0; t < 4; ++t) {
            #pragma unroll
            for (int dt = 0; dt < 4; ++dt) {
                half4 bv = *(const half4*)&Vts[buf][(dt * 16 + col) * KPAD + t * 16 + quad * 4];
                #pragma unroll
                for (int st = 0; st < 2; ++st)
                    o[st][dt] = __builtin_amdgcn_mfma_f32_16x16x16f16(pa[st][t], bv, o[st][dt], 0, 0, 0);
            }
            #pragma unroll
            for (int st = 0; st < 2; ++st)
                lacc[st] = __builtin_amdgcn_mfma_f32_16x16x16f16(pa[st][t], bone, lacc[st], 0, 0, 0);
        }

        __syncthreads();   // single barrier: buf^1 visible, buf reads done
    }

    // Epilogue: unnormalized partial O (fp16) + stats (m lane-space, l row-space)
    const size_t pbase = (size_t)kz * HEAD_ELEMS + base;
    #pragma unroll
    for (int st = 0; st < 2; ++st) {
        #pragma unroll
        for (int dt = 0; dt < 4; ++dt)
            #pragma unroll
            for (int i = 0; i < 4; ++i) {
                int row = q0 + wid * 32 + st * 16 + quad * 4 + i;
                pO[pbase + (size_t)row * DH + dt * 16 + col] = (half_t)o[st][dt][i];
            }
        if (quad == 0) {
            int row = q0 + wid * 32 + st * 16 + col;
            mst[kz * NQROWS + bh * SS + row] = m_i[st];
        }
        if (col == 0) {
            #pragma unroll
            for (int r = 0; r < 4; ++r) {
                int row = q0 + wid * 32 + st * 16 + quad * 4 + r;
                lst[kz * NQROWS + bh * SS + row] = lacc[st][r];
            }
        }
    }
}

// ---------------------------------------------------------------------------
// merge: combine the two kz partials (unnormalized O, exp2-domain m).
// ---------------------------------------------------------------------------
__global__ __launch_bounds__(256) void merge(const half_t* __restrict__ pO,
                                             const float* __restrict__ mst,
                                             const float* __restrict__ lst,
                                             float* __restrict__ out) {
    int gid = blockIdx.x * 256 + threadIdx.x;   // 0..262143
    int row = gid >> 3;                         // bh*SS + s
    int dc  = (gid & 7) * 8;
    float m1 = mst[row], m2 = mst[NQROWS + row];
    float l1 = lst[row], l2 = lst[NQROWS + row];
    float M  = fmaxf(m1, m2);
    float e1 = exp2f(m1 - M);
    float e2 = exp2f(m2 - M);
    float inv = 1.0f / (l1 * e1 + l2 * e2);
    float a = e1 * inv, b = e2 * inv;
    half8 o1 = *(const half8*)&pO[(size_t)row * DH + dc];
    half8 o2 = *(const half8*)&pO[(size_t)HEAD_ELEMS + (size_t)row * DH + dc];
    float4 r0, r1;
    r0.x = a * (float)o1[0] + b * (float)o2[0];
    r0.y = a * (float)o1[1] + b * (float)o2[1];
    r0.z = a * (float)o1[2] + b * (float)o2[2];
    r0.w = a * (float)o1[3] + b * (float)o2[3];
    r1.x = a * (float)o1[4] + b * (float)o2[4];
    r1.y = a * (float)o1[5] + b * (float)o2[5];
    r1.z = a * (float)o1[6] + b * (float)o2[6];
    r1.w = a * (float)o1[7] + b * (float)o2[7];
    *(float4*)&out[(size_t)row * DH + dc]     = r0;
    *(float4*)&out[(size_t)row * DH + dc + 4] = r1;
}

extern "C" void kernel_launch(void* const* d_in, const int* in_sizes, int n_in,
                              void* d_out, int out_size, void* d_ws, size_t ws_size,
                              hipStream_t stream) {
    const float* x  = (const float*)d_in[0];   // [4,2048,256]
    const float* Wq = (const float*)d_in[1];   // [768,256]
    const float* bq = (const float*)d_in[2];   // [768]
    float* out = (float*)d_out;                // [4,4,2048,64]

    // ws layout (half_t units):
    //   qh 0..2M | kh 2M..4M | vt 4M..6M | xh 6M..8M | xl 8M..10M | Wh 10M..10.19M
    //   pO[2] aliases xh/xl (dead after qkv_proj); stats f32 after Wh.
    half_t* qh  = (half_t*)d_ws;
    half_t* kh  = qh + (size_t)HEAD_ELEMS;
    half_t* vt  = kh + (size_t)HEAD_ELEMS;
    half_t* xh  = vt + (size_t)HEAD_ELEMS;
    half_t* xl  = xh + (size_t)HEAD_ELEMS;
    half_t* whp = xl + (size_t)HEAD_ELEMS;             // 196608 halfs
    half_t* pO  = xh;                                  // alias: 2 x HEAD_ELEMS
    float*  mst = (float*)((char*)d_ws + 21364736);    // 2*32768 floats
    float*  lst = mst + 2 * NQROWS;

    prep<<<2048, 256, 0, stream>>>(x, Wq, xh, xl, whp);
    qkv_proj<<<dim3(NROW / 64, NE / 64), 256, 0, stream>>>(xh, xl, whp, bq, qh, kh, vt);
    attn<<<dim3(SS / 64, BH, 2), 128, 0, stream>>>(qh, kh, vt, pO, mst, lst);
    merge<<<1024, 256, 0, stream>>>(pO, mst, lst, out);
}